// Round 1
// baseline (286.938 us; speedup 1.0000x reference)
//
#include <hip/hip_runtime.h>

// shading(p) = n^T M n with n=(x,y,z,1), M symmetric from 9 SH coeffs.
// Expanded quadratic form: 10 per-batch scalars, ~10 FMA/pixel. Memory-bound:
// 268 MB total traffic -> ~43 us roofline at 6.3 TB/s.

__global__ __launch_bounds__(256) void shade_kernel(
    const float* __restrict__ light,     // [B,9]
    const float* __restrict__ normals,   // [B,3,W,H]
    float* __restrict__ out,             // [B,1,W,H]
    int WH)                              // W*H (512*512)
{
    const int b = blockIdx.y;
    const float* L = light + b * 9;

    const float C1 = 0.429043f, C2 = 0.511664f, C3 = 0.743152f,
                C4 = 0.886227f, C5 = 0.247708f;

    // wave-uniform (same b for whole block) -> scalar loads + broadcast
    const float L0 = L[0], L1 = L[1], L2 = L[2], L3 = L[3], L4 = L[4],
                L5 = L[5], L6 = L[6], L7 = L[7], L8 = L[8];

    const float axx =  C1 * L8;            // x^2
    const float ayy = -C1 * L8;            // y^2
    const float azz =  C3 * L6;            // z^2
    const float axy = 2.0f * C1 * L4;      // x*y
    const float axz = 2.0f * C1 * L7;      // x*z
    const float ayz = 2.0f * C1 * L5;      // y*z
    const float ax  = 2.0f * C2 * L3;      // x
    const float ay  = 2.0f * C2 * L1;      // y
    const float az  = 2.0f * C2 * L2;      // z
    const float a0  = C4 * L0 - C5 * L6;   // const

    const size_t base = (size_t)b * 3u * (size_t)WH;
    const float4* __restrict__ nx = (const float4*)(normals + base);
    const float4* __restrict__ ny = (const float4*)(normals + base + (size_t)WH);
    const float4* __restrict__ nz = (const float4*)(normals + base + 2u * (size_t)WH);
    float4* __restrict__ o = (float4*)(out + (size_t)b * (size_t)WH);

    const int i = blockIdx.x * blockDim.x + threadIdx.x;   // float4-group index

    const float4 x = nx[i];
    const float4 y = ny[i];
    const float4 z = nz[i];

    float4 r;
#define SHADE(c)                                                         \
    {                                                                    \
        const float xx = x.c, yy = y.c, zz = z.c;                        \
        float s = a0;                                                    \
        s = fmaf(xx, fmaf(axx, xx, fmaf(axy, yy, fmaf(axz, zz, ax))), s);\
        s = fmaf(yy, fmaf(ayy, yy, fmaf(ayz, zz, ay)), s);               \
        s = fmaf(zz, fmaf(azz, zz, az), s);                              \
        r.c = s;                                                         \
    }
    SHADE(x); SHADE(y); SHADE(z); SHADE(w);
#undef SHADE

    o[i] = r;
}

extern "C" void kernel_launch(void* const* d_in, const int* in_sizes, int n_in,
                              void* d_out, int out_size, void* d_ws, size_t ws_size,
                              hipStream_t stream) {
    const float* light   = (const float*)d_in[0];   // [B,9] fp32
    const float* normals = (const float*)d_in[1];   // [B,3,512,512] fp32
    float* out = (float*)d_out;                     // [B,1,512,512] fp32

    const int B  = in_sizes[0] / 9;                 // 64
    const int WH = in_sizes[1] / (B * 3);           // 262144

    const int threads = 256;
    const int v4_per_batch = WH / 4;                // 65536
    dim3 grid(v4_per_batch / threads, B);           // (256, 64)

    shade_kernel<<<grid, dim3(threads), 0, stream>>>(light, normals, out, WH);
}